// Round 1
// 440.197 us; speedup vs baseline: 1.0248x; 1.0248x over previous
//
#include <hip/hip_runtime.h>
#include <hip/hip_fp16.h>

#define N_NODES 100000
#define N_EDGES 1600000
#define IN_CH   128
#define NHID    64
#define OUT_CH  40
#define NBLK    391    // ceil(N_NODES/256)
#define NBUCK   196    // ceil(N_NODES/512)
#define BCAP    8960   // fixed bucket capacity (mean 8163, +8 sigma)

// ---------------- rowptr scans ----------------

__global__ __launch_bounds__(256) void k_scan1(const int* __restrict__ cnt,
                                               int* __restrict__ rowptr,
                                               int* __restrict__ bsum) {
    __shared__ int s[256];
    int t = threadIdx.x;
    int n = blockIdx.x * 256 + t;
    int v = (n < N_NODES) ? cnt[n] : 0;
    s[t] = v;
    __syncthreads();
    for (int off = 1; off < 256; off <<= 1) {
        int add = (t >= off) ? s[t - off] : 0;
        __syncthreads();
        s[t] += add;
        __syncthreads();
    }
    int incl = s[t];
    if (n < N_NODES) rowptr[n] = incl - v;
    if (t == 255) bsum[blockIdx.x] = incl;
}

__global__ __launch_bounds__(512) void k_scan2(int* __restrict__ bsum) {
    __shared__ int s[512];
    int t = threadIdx.x;
    int v = (t < NBLK) ? bsum[t] : 0;
    s[t] = v;
    __syncthreads();
    for (int off = 1; off < 512; off <<= 1) {
        int add = (t >= off) ? s[t - off] : 0;
        __syncthreads();
        s[t] += add;
        __syncthreads();
    }
    if (t < NBLK) bsum[t] = s[t] - v;
}

__global__ __launch_bounds__(256) void k_scan3(const int* __restrict__ cnt,
                                               const int* __restrict__ bsum,
                                               int* __restrict__ rowptr,
                                               float* __restrict__ dinv) {
    int n = blockIdx.x * 256 + threadIdx.x;
    if (n < N_NODES) {
        int rp = rowptr[n] + bsum[n >> 8];
        rowptr[n] = rp;
        int c = cnt[n];
        dinv[n] = (c > 0) ? rsqrtf((float)c) : 0.0f;
    }
    if (blockIdx.x == 0 && threadIdx.x == 0) rowptr[N_NODES] = N_EDGES;
}

// ---- scatter pass A: fixed-capacity buckets by c>>9 (pure bucketing, no cnt) ----

__global__ __launch_bounds__(256) void k_scatA(const int* __restrict__ ei,
                                               int* __restrict__ bucketCnt,
                                               int2* __restrict__ ebufA) {
    __shared__ int hist[NBUCK];
    __shared__ int base[NBUCK];
    int t = threadIdx.x;
    int chunk = blockIdx.x * 4096;
    for (int i = t; i < NBUCK; i += 256) hist[i] = 0;
    __syncthreads();
#pragma unroll 4
    for (int i = 0; i < 16; i++) {
        int e = chunk + i * 256 + t;
        if (e < N_EDGES) atomicAdd(&hist[ei[N_EDGES + e] >> 9], 1);
    }
    __syncthreads();
    for (int b = t; b < NBUCK; b += 256) {
        int h = hist[b];
        base[b] = h ? atomicAdd(&bucketCnt[b], h) : 0;
    }
    __syncthreads();
#pragma unroll 4
    for (int i = 0; i < 16; i++) {
        int e = chunk + i * 256 + t;
        if (e < N_EDGES) {
            int r = ei[e], c = ei[N_EDGES + e];
            int pos = atomicAdd(&base[c >> 9], 1);
            ebufA[(size_t)(c >> 9) * BCAP + pos] = make_int2(r, c);
        }
    }
}

// ---- degree count from bucketed edges: contiguous read, LDS histogram ----

__global__ __launch_bounds__(256) void k_deg(const int2* __restrict__ ebufA,
                                             const int* __restrict__ bucketCnt,
                                             int* __restrict__ cnt) {
    __shared__ int hist[512];
    int b = blockIdx.x;
    int nodeB = b * 512;
    int t = threadIdx.x;
    for (int i = t; i < 512; i += 256) hist[i] = 0;
    __syncthreads();
    int nE = bucketCnt[b];
    const int2* src = ebufA + (size_t)b * BCAP;
    for (int i = t; i < nE; i += 256) atomicAdd(&hist[src[i].y - nodeB], 1);
    __syncthreads();
    for (int i = t; i < 512; i += 256) {
        int node = nodeB + i;
        if (node < N_NODES) cnt[node] = hist[i];
    }
}

// ---- scatter pass B: within bucket, per-NODE cursors -> exact CSR order ----

__global__ __launch_bounds__(256) void k_scatB(const int2* __restrict__ ebufA,
                                               const int* __restrict__ bucketCnt,
                                               const float* __restrict__ dinv,
                                               const int* __restrict__ rowptr,
                                               int2* __restrict__ e8) {
    __shared__ int lcur[512];
    int b = blockIdx.x;
    int nodeB = b * 512;
    int t = threadIdx.x;
    for (int i = t; i < 512; i += 256) {
        int node = nodeB + i;
        lcur[i] = (node < N_NODES) ? rowptr[node] : 0;
    }
    __syncthreads();
    int nE = bucketCnt[b];
    const int2* src = ebufA + (size_t)b * BCAP;
    for (int i = t; i < nE; i += 256) {
        int2 rc = src[i];
        float w = dinv[rc.x] * dinv[rc.y];
        int pos = atomicAdd(&lcur[rc.y - nodeB], 1);
        e8[pos] = make_int2(rc.x, __float_as_int(w));
    }
}

// ---- pack 4 floats -> 4 halves (8B) ----
__device__ __forceinline__ void store_h4(__half* dst, float a, float b, float c, float d) {
    union { uint2 u; __half2 h[2]; } pk;
    pk.h[0] = __floats2half2_rn(a, b);
    pk.h[1] = __floats2half2_rn(c, d);
    *(uint2*)dst = pk.u;
}

// ---------------- fc1: h0 = relu(x @ fc1_w^T + b); also fp16 copy ----------------
// Rewritten: no transposed-weight LDS tile (the old wT[k][o] staging was a 64-way
// bank-conflict write, ~8k LDS cycles/block = the 1.36e7 SQ_LDS_BANK_CONFLICT).
// - w rows [o][k] are read directly from global: o sits on ty, so each b-load is a
//   4-address broadcast -> 4 L1 lines/instr, w (32KB) is L1-resident.
// - nodes sit on tx; xs is stride-128 with float4-granular XOR swizzle
//   (kg' = kg ^ ((row>>2)&7)) so 16-distinct-row reads spread over 8 bank groups.
// - LDS 66.5KB -> 32KB: 4 blocks/CU instead of 2.

__global__ __launch_bounds__(256, 4) void k_fc1(const float* __restrict__ x,
                                                const float* __restrict__ w,
                                                const float* __restrict__ b,
                                                float* __restrict__ h0,
                                                __half* __restrict__ h016) {
    __shared__ float xs[64 * 128];     // [row][kg^swz] at float4 granularity
    int t = threadIdx.x;
    int nodeBase = blockIdx.x * 64;

    {
        int nl = t >> 2, seg = t & 3;
        int n = nodeBase + nl;
        int swz = (nl >> 2) & 7;
        float4* dstrow = (float4*)(xs + nl * 128);
        if (n < N_NODES) {
            const float4* src = (const float4*)(x + (size_t)n * IN_CH + seg * 32);
#pragma unroll
            for (int q = 0; q < 8; q++) dstrow[(seg * 8 + q) ^ swz] = src[q];
        } else {
            float4 z = {0.f, 0.f, 0.f, 0.f};
#pragma unroll
            for (int q = 0; q < 8; q++) dstrow[(seg * 8 + q) ^ swz] = z;
        }
    }
    __syncthreads();

    int tx = t & 15, ty = t >> 4;
    int n0 = tx * 4, o0 = ty * 4;     // nodes on tx, outputs on ty
    int swz = tx & 7;                 // (row>>2)&7 == tx for rows n0..n0+3
    const float4* xrow0 = (const float4*)(xs + (n0 + 0) * 128);
    const float4* xrow1 = (const float4*)(xs + (n0 + 1) * 128);
    const float4* xrow2 = (const float4*)(xs + (n0 + 2) * 128);
    const float4* xrow3 = (const float4*)(xs + (n0 + 3) * 128);

    float c[4][4];
#pragma unroll
    for (int i = 0; i < 4; i++)
#pragma unroll
        for (int j = 0; j < 4; j++) c[i][j] = 0.f;

#pragma unroll 4
    for (int k = 0; k < IN_CH; k += 4) {
        int kg = (k >> 2) ^ swz;
        float4 b0 = *(const float4*)&w[(size_t)(o0 + 0) * IN_CH + k];
        float4 b1 = *(const float4*)&w[(size_t)(o0 + 1) * IN_CH + k];
        float4 b2 = *(const float4*)&w[(size_t)(o0 + 2) * IN_CH + k];
        float4 b3 = *(const float4*)&w[(size_t)(o0 + 3) * IN_CH + k];
        float4 a0 = xrow0[kg];
        float4 a1 = xrow1[kg];
        float4 a2 = xrow2[kg];
        float4 a3 = xrow3[kg];
#pragma unroll
        for (int i = 0; i < 4; i++) {
            float4 a = (i == 0) ? a0 : (i == 1) ? a1 : (i == 2) ? a2 : a3;
            c[i][0] = fmaf(a.x, b0.x, fmaf(a.y, b0.y, fmaf(a.z, b0.z, fmaf(a.w, b0.w, c[i][0]))));
            c[i][1] = fmaf(a.x, b1.x, fmaf(a.y, b1.y, fmaf(a.z, b1.z, fmaf(a.w, b1.w, c[i][1]))));
            c[i][2] = fmaf(a.x, b2.x, fmaf(a.y, b2.y, fmaf(a.z, b2.z, fmaf(a.w, b2.w, c[i][2]))));
            c[i][3] = fmaf(a.x, b3.x, fmaf(a.y, b3.y, fmaf(a.z, b3.z, fmaf(a.w, b3.w, c[i][3]))));
        }
    }

    float4 bias = *(const float4*)&b[o0];
#pragma unroll
    for (int i = 0; i < 4; i++) {
        int n = nodeBase + n0 + i;
        if (n < N_NODES) {
            float4 v;
            v.x = fmaxf(c[i][0] + bias.x, 0.f);
            v.y = fmaxf(c[i][1] + bias.y, 0.f);
            v.z = fmaxf(c[i][2] + bias.z, 0.f);
            v.w = fmaxf(c[i][3] + bias.w, 0.f);
            *(float4*)&h0[(size_t)n * NHID + o0] = v;
            store_h4(&h016[(size_t)n * NHID + o0], v.x, v.y, v.z, v.w);
        }
    }
}

// ------- fused GCN2Conv layer: 8-lane walks, software-pipelined meta->value chain -------
// 8 lanes per node (lane = 8 channels, one dwordx4 = full 128B row per group).
// Pipeline: prefetch batch j+1 (4 metas + 4 values) while FMA-ing batch j, so
// the serial meta->gather dependence of consecutive batches overlaps.

__global__ __launch_bounds__(256, 4) void k_conv(const __half* __restrict__ hin,
                                                 const float* __restrict__ h0,
                                                 const int* __restrict__ rowptr,
                                                 const int2* __restrict__ e8,
                                                 const float* __restrict__ W,   // [c][o] 64x64
                                                 __half* __restrict__ hout) {
    __shared__ float mix[32 * 68];
    int t = threadIdx.x;
    int nodeBase = blockIdx.x * 32;      // N_NODES % 32 == 0
    int grp = t >> 3;                    // 32 groups of 8 lanes -> 1 node each
    int cg = (t & 7) * 8;                // 8 channels per lane

    int n = nodeBase + grp;
    int s = rowptr[n], e = rowptr[n + 1];
    int d = e - s;
    int hi = (d > 0) ? (e - 1) : 0;

    float acc[8];
#pragma unroll
    for (int i = 0; i < 8; i++) acc[i] = 0.f;

    int2  pm[4];
    float4 pv[4];
    if (d > 0) {
#pragma unroll
        for (int u = 0; u < 4; u++) pm[u] = e8[min(s + u, hi)];
#pragma unroll
        for (int u = 0; u < 4; u++) pv[u] = *(const float4*)&hin[(size_t)pm[u].x * NHID + cg];
    }

    for (int j = s; j < e; j += 4) {
        int2  cm[4];
        float4 cv[4];
#pragma unroll
        for (int u = 0; u < 4; u++) { cm[u] = pm[u]; cv[u] = pv[u]; }
        int jn = j + 4;
        if (jn < e) {
#pragma unroll
            for (int u = 0; u < 4; u++) pm[u] = e8[min(jn + u, hi)];
#pragma unroll
            for (int u = 0; u < 4; u++) pv[u] = *(const float4*)&hin[(size_t)pm[u].x * NHID + cg];
        }
#pragma unroll
        for (int u = 0; u < 4; u++) {
            float wgt = (j + u < e) ? __int_as_float(cm[u].y) : 0.f;
            const __half2* hp = (const __half2*)&cv[u];
#pragma unroll
            for (int q = 0; q < 4; q++) {
                float2 f = __half22float2(hp[q]);
                acc[q * 2 + 0] = fmaf(wgt, f.x, acc[q * 2 + 0]);
                acc[q * 2 + 1] = fmaf(wgt, f.y, acc[q * 2 + 1]);
            }
        }
    }

    {
        float4 h0a = *(const float4*)&h0[(size_t)n * NHID + cg];
        float4 h0b = *(const float4*)&h0[(size_t)n * NHID + cg + 4];
        float4 m0, m1;
        m0.x = fmaf(0.9f, acc[0], 0.1f * h0a.x);
        m0.y = fmaf(0.9f, acc[1], 0.1f * h0a.y);
        m0.z = fmaf(0.9f, acc[2], 0.1f * h0a.z);
        m0.w = fmaf(0.9f, acc[3], 0.1f * h0a.w);
        m1.x = fmaf(0.9f, acc[4], 0.1f * h0b.x);
        m1.y = fmaf(0.9f, acc[5], 0.1f * h0b.y);
        m1.z = fmaf(0.9f, acc[6], 0.1f * h0b.z);
        m1.w = fmaf(0.9f, acc[7], 0.1f * h0b.w);
        *(float4*)&mix[grp * 68 + cg] = m0;
        *(float4*)&mix[grp * 68 + cg + 4] = m1;
    }
    __syncthreads();

    // GEMM 32x64, 2x4 acc per thread; W rows broadcast via L1; fp16 output
    int tx = t & 15, ty = t >> 4;
    int o0 = tx * 4, r0 = ty * 2;
    float c[2][4];
#pragma unroll
    for (int i = 0; i < 2; i++)
#pragma unroll
        for (int j = 0; j < 4; j++) c[i][j] = 0.f;

#pragma unroll 4
    for (int k = 0; k < NHID; k += 4) {
        float4 b0 = *(const float4*)&W[(k + 0) * NHID + o0];
        float4 b1 = *(const float4*)&W[(k + 1) * NHID + o0];
        float4 b2 = *(const float4*)&W[(k + 2) * NHID + o0];
        float4 b3 = *(const float4*)&W[(k + 3) * NHID + o0];
#pragma unroll
        for (int i = 0; i < 2; i++) {
            float4 a = *(const float4*)&mix[(r0 + i) * 68 + k];
            c[i][0] = fmaf(a.x, b0.x, fmaf(a.y, b1.x, fmaf(a.z, b2.x, fmaf(a.w, b3.x, c[i][0]))));
            c[i][1] = fmaf(a.x, b0.y, fmaf(a.y, b1.y, fmaf(a.z, b2.y, fmaf(a.w, b3.y, c[i][1]))));
            c[i][2] = fmaf(a.x, b0.z, fmaf(a.y, b1.z, fmaf(a.z, b2.z, fmaf(a.w, b3.z, c[i][2]))));
            c[i][3] = fmaf(a.x, b0.w, fmaf(a.y, b1.w, fmaf(a.z, b2.w, fmaf(a.w, b3.w, c[i][3]))));
        }
    }
#pragma unroll
    for (int i = 0; i < 2; i++) {
        int n2 = nodeBase + r0 + i;
        store_h4(&hout[(size_t)n2 * NHID + o0],
                 fmaxf(c[i][0], 0.f), fmaxf(c[i][1], 0.f),
                 fmaxf(c[i][2], 0.f), fmaxf(c[i][3], 0.f));
    }
}

// ---------------- fc2: out = h @ fc2_w^T + b (h in fp16) ----------------

__global__ __launch_bounds__(256) void k_fc2(const __half* __restrict__ h,
                                             const float* __restrict__ w,
                                             const float* __restrict__ b,
                                             float* __restrict__ out) {
    __shared__ float wT[NHID * 44];
    __shared__ float hs[64 * 68];
    int t = threadIdx.x;
    int nodeBase = blockIdx.x * 64;

    for (int id = t; id < NHID * OUT_CH; id += 256) {
        int o = id >> 6, k = id & 63;
        wT[k * 44 + o] = w[id];
    }
    {
        int nl = t >> 2, seg = t & 3;
        int n = nodeBase + nl;
        float* dst = hs + nl * 68 + seg * 16;
        if (n < N_NODES) {
            float4 raw0 = *(const float4*)&h[(size_t)n * NHID + seg * 16];
            float4 raw1 = *(const float4*)&h[(size_t)n * NHID + seg * 16 + 8];
            const __half2* hp0 = (const __half2*)&raw0;
            const __half2* hp1 = (const __half2*)&raw1;
#pragma unroll
            for (int q = 0; q < 4; q++) {
                float2 f = __half22float2(hp0[q]);
                dst[q * 2 + 0] = f.x;
                dst[q * 2 + 1] = f.y;
            }
#pragma unroll
            for (int q = 0; q < 4; q++) {
                float2 f = __half22float2(hp1[q]);
                dst[8 + q * 2 + 0] = f.x;
                dst[8 + q * 2 + 1] = f.y;
            }
        } else {
#pragma unroll
            for (int q = 0; q < 16; q++) dst[q] = 0.f;
        }
    }
    __syncthreads();

    if (t < 160) {
        int tx = t % 10, ty = t / 10;
        int o0 = tx * 4, n0 = ty * 4;
        float c[4][4];
#pragma unroll
        for (int i = 0; i < 4; i++)
#pragma unroll
            for (int j = 0; j < 4; j++) c[i][j] = 0.f;

#pragma unroll 4
        for (int k = 0; k < NHID; k += 4) {
            float4 b0 = *(const float4*)&wT[(k + 0) * 44 + o0];
            float4 b1 = *(const float4*)&wT[(k + 1) * 44 + o0];
            float4 b2 = *(const float4*)&wT[(k + 2) * 44 + o0];
            float4 b3 = *(const float4*)&wT[(k + 3) * 44 + o0];
#pragma unroll
            for (int i = 0; i < 4; i++) {
                float4 a = *(const float4*)&hs[(n0 + i) * 68 + k];
                c[i][0] = fmaf(a.x, b0.x, fmaf(a.y, b1.x, fmaf(a.z, b2.x, fmaf(a.w, b3.x, c[i][0]))));
                c[i][1] = fmaf(a.x, b0.y, fmaf(a.y, b1.y, fmaf(a.z, b2.y, fmaf(a.w, b3.y, c[i][1]))));
                c[i][2] = fmaf(a.x, b0.z, fmaf(a.y, b1.z, fmaf(a.z, b2.z, fmaf(a.w, b3.z, c[i][2]))));
                c[i][3] = fmaf(a.x, b0.w, fmaf(a.y, b1.w, fmaf(a.z, b2.w, fmaf(a.w, b3.w, c[i][3]))));
            }
        }
        float4 bias = *(const float4*)&b[o0];
#pragma unroll
        for (int i = 0; i < 4; i++) {
            int n = nodeBase + n0 + i;
            if (n < N_NODES) {
                float4 v;
                v.x = c[i][0] + bias.x;
                v.y = c[i][1] + bias.y;
                v.z = c[i][2] + bias.z;
                v.w = c[i][3] + bias.w;
                *(float4*)&out[(size_t)n * OUT_CH + o0] = v;
            }
        }
    }
}

// ---------------- launch ----------------

extern "C" void kernel_launch(void* const* d_in, const int* in_sizes, int n_in,
                              void* d_out, int out_size, void* d_ws, size_t ws_size,
                              hipStream_t stream) {
    const float* x    = (const float*)d_in[0];
    const int*   ei   = (const int*)d_in[1];
    const float* fc1w = (const float*)d_in[3];
    const float* fc1b = (const float*)d_in[4];
    const float* cw   = (const float*)d_in[5];
    const float* fc2w = (const float*)d_in[6];
    const float* fc2b = (const float*)d_in[7];
    float* out = (float*)d_out;

    char* p = (char*)d_ws;
    auto alloc = [&](size_t bytes) { char* r = p; p += (bytes + 255) & ~(size_t)255; return r; };
    float*  h0     = (float*) alloc((size_t)N_NODES * NHID * 4);
    __half* h016   = (__half*)alloc((size_t)N_NODES * NHID * 2);
    __half* ha16   = (__half*)alloc((size_t)N_NODES * NHID * 2);
    __half* hb16   = (__half*)alloc((size_t)N_NODES * NHID * 2);
    int2*   e8     = (int2*)  alloc(((size_t)N_EDGES + 8) * 8);
    int2*   ebufA  = (int2*)  alloc((size_t)NBUCK * BCAP * 8);   // 14.05 MB fixed-cap buckets
    int*    cnt    = (int*)   alloc((size_t)N_NODES * 4);
    int*    rowptr = (int*)   alloc((size_t)(N_NODES + 1) * 4);
    int*    bCnt   = (int*)   alloc((size_t)NBUCK * 4);
    float*  dinv   = (float*) alloc((size_t)N_NODES * 4);
    int*    bsum   = (int*)   alloc(512 * 4);

    hipMemsetAsync(bCnt, 0, (size_t)NBUCK * 4, stream);
    k_scatA<<<(N_EDGES + 4095) / 4096, 256, 0, stream>>>(ei, bCnt, ebufA);
    k_deg  <<<NBUCK, 256, 0, stream>>>(ebufA, bCnt, cnt);
    k_scan1<<<NBLK, 256, 0, stream>>>(cnt, rowptr, bsum);
    k_scan2<<<1, 512, 0, stream>>>(bsum);
    k_scan3<<<NBLK, 256, 0, stream>>>(cnt, bsum, rowptr, dinv);
    k_scatB<<<NBUCK, 256, 0, stream>>>(ebufA, bCnt, dinv, rowptr, e8);

    int gb64 = (N_NODES + 63) / 64;   // 1563
    int gb32 = N_NODES / 32;          // 3125
    k_fc1 <<<gb64, 256, 0, stream>>>(x, fc1w, fc1b, h0, h016);
    k_conv<<<gb32, 256, 0, stream>>>(h016, h0, rowptr, e8, cw + 0 * NHID * NHID, ha16);
    k_conv<<<gb32, 256, 0, stream>>>(ha16, h0, rowptr, e8, cw + 1 * NHID * NHID, hb16);
    k_conv<<<gb32, 256, 0, stream>>>(hb16, h0, rowptr, e8, cw + 2 * NHID * NHID, ha16);
    k_conv<<<gb32, 256, 0, stream>>>(ha16, h0, rowptr, e8, cw + 3 * NHID * NHID, hb16);
    k_fc2 <<<gb64, 256, 0, stream>>>(hb16, fc2w, fc2b, out);
}

// Round 2
// 425.779 us; speedup vs baseline: 1.0595x; 1.0339x over previous
//
#include <hip/hip_runtime.h>
#include <hip/hip_fp16.h>

#define N_NODES 100000
#define N_EDGES 1600000
#define IN_CH   128
#define NHID    64
#define OUT_CH  40
#define NBLK    391    // ceil(N_NODES/256)
#define NBUCK   196    // ceil(N_NODES/512)
#define BCAP    8960   // fixed bucket capacity (mean 8163, +8 sigma)
#define ECAP    1024   // per-block edge stage (mean 512, sigma 22.6 -> +22 sigma)

// ---------------- rowptr scans ----------------

__global__ __launch_bounds__(256) void k_scan1(const int* __restrict__ cnt,
                                               int* __restrict__ rowptr,
                                               int* __restrict__ bsum) {
    __shared__ int s[256];
    int t = threadIdx.x;
    int n = blockIdx.x * 256 + t;
    int v = (n < N_NODES) ? cnt[n] : 0;
    s[t] = v;
    __syncthreads();
    for (int off = 1; off < 256; off <<= 1) {
        int add = (t >= off) ? s[t - off] : 0;
        __syncthreads();
        s[t] += add;
        __syncthreads();
    }
    int incl = s[t];
    if (n < N_NODES) rowptr[n] = incl - v;
    if (t == 255) bsum[blockIdx.x] = incl;
}

__global__ __launch_bounds__(512) void k_scan2(int* __restrict__ bsum) {
    __shared__ int s[512];
    int t = threadIdx.x;
    int v = (t < NBLK) ? bsum[t] : 0;
    s[t] = v;
    __syncthreads();
    for (int off = 1; off < 512; off <<= 1) {
        int add = (t >= off) ? s[t - off] : 0;
        __syncthreads();
        s[t] += add;
        __syncthreads();
    }
    if (t < NBLK) bsum[t] = s[t] - v;
}

__global__ __launch_bounds__(256) void k_scan3(const int* __restrict__ cnt,
                                               const int* __restrict__ bsum,
                                               int* __restrict__ rowptr,
                                               float* __restrict__ dinv) {
    int n = blockIdx.x * 256 + threadIdx.x;
    if (n < N_NODES) {
        int rp = rowptr[n] + bsum[n >> 8];
        rowptr[n] = rp;
        int c = cnt[n];
        dinv[n] = (c > 0) ? rsqrtf((float)c) : 0.0f;
    }
    if (blockIdx.x == 0 && threadIdx.x == 0) rowptr[N_NODES] = N_EDGES;
}

// ---- scatter pass A: fixed-capacity buckets by c>>9 (pure bucketing, no cnt) ----

__global__ __launch_bounds__(256) void k_scatA(const int* __restrict__ ei,
                                               int* __restrict__ bucketCnt,
                                               int2* __restrict__ ebufA) {
    __shared__ int hist[NBUCK];
    __shared__ int base[NBUCK];
    int t = threadIdx.x;
    int chunk = blockIdx.x * 4096;
    for (int i = t; i < NBUCK; i += 256) hist[i] = 0;
    __syncthreads();
#pragma unroll 4
    for (int i = 0; i < 16; i++) {
        int e = chunk + i * 256 + t;
        if (e < N_EDGES) atomicAdd(&hist[ei[N_EDGES + e] >> 9], 1);
    }
    __syncthreads();
    for (int b = t; b < NBUCK; b += 256) {
        int h = hist[b];
        base[b] = h ? atomicAdd(&bucketCnt[b], h) : 0;
    }
    __syncthreads();
#pragma unroll 4
    for (int i = 0; i < 16; i++) {
        int e = chunk + i * 256 + t;
        if (e < N_EDGES) {
            int r = ei[e], c = ei[N_EDGES + e];
            int pos = atomicAdd(&base[c >> 9], 1);
            ebufA[(size_t)(c >> 9) * BCAP + pos] = make_int2(r, c);
        }
    }
}

// ---- degree count from bucketed edges: contiguous read, LDS histogram ----

__global__ __launch_bounds__(256) void k_deg(const int2* __restrict__ ebufA,
                                             const int* __restrict__ bucketCnt,
                                             int* __restrict__ cnt) {
    __shared__ int hist[512];
    int b = blockIdx.x;
    int nodeB = b * 512;
    int t = threadIdx.x;
    for (int i = t; i < 512; i += 256) hist[i] = 0;
    __syncthreads();
    int nE = bucketCnt[b];
    const int2* src = ebufA + (size_t)b * BCAP;
    for (int i = t; i < nE; i += 256) atomicAdd(&hist[src[i].y - nodeB], 1);
    __syncthreads();
    for (int i = t; i < 512; i += 256) {
        int node = nodeB + i;
        if (node < N_NODES) cnt[node] = hist[i];
    }
}

// ---- scatter pass B: within bucket, per-NODE cursors -> exact CSR order ----

__global__ __launch_bounds__(256) void k_scatB(const int2* __restrict__ ebufA,
                                               const int* __restrict__ bucketCnt,
                                               const float* __restrict__ dinv,
                                               const int* __restrict__ rowptr,
                                               int2* __restrict__ e8) {
    __shared__ int lcur[512];
    int b = blockIdx.x;
    int nodeB = b * 512;
    int t = threadIdx.x;
    for (int i = t; i < 512; i += 256) {
        int node = nodeB + i;
        lcur[i] = (node < N_NODES) ? rowptr[node] : 0;
    }
    __syncthreads();
    int nE = bucketCnt[b];
    const int2* src = ebufA + (size_t)b * BCAP;
    for (int i = t; i < nE; i += 256) {
        int2 rc = src[i];
        float w = dinv[rc.x] * dinv[rc.y];
        int pos = atomicAdd(&lcur[rc.y - nodeB], 1);
        e8[pos] = make_int2(rc.x, __float_as_int(w));
    }
}

// ---- pack 4 floats -> 4 halves (8B) ----
__device__ __forceinline__ void store_h4(__half* dst, float a, float b, float c, float d) {
    union { uint2 u; __half2 h[2]; } pk;
    pk.h[0] = __floats2half2_rn(a, b);
    pk.h[1] = __floats2half2_rn(c, d);
    *(uint2*)dst = pk.u;
}

// ---------------- fc1: h0 = relu(x @ fc1_w^T + b); also fp16 copy ----------------
// xs swizzle: swz(row) = (row ^ (row>>3)) & 7 at float4 granularity.
// Proof: staging write (fixed q): lanes cover 16 rows x 4 segs; seg*8 == 0 mod 8 so
// bank-group = (q ^ swz(row))&7; swz over any aligned 16-row run hits each of 8
// values exactly twice -> 8 groups x 8 lanes, conflict-free for b128.
// Compute read (fixed k,i): rows 4*tx+i; swz = (4(tx&1)+i) ^ (tx>>1) -> 16 tx give
// each group exactly twice; ty lanes broadcast. Conflict-free.

__global__ __launch_bounds__(256, 4) void k_fc1(const float* __restrict__ x,
                                                const float* __restrict__ w,
                                                const float* __restrict__ b,
                                                float* __restrict__ h0,
                                                __half* __restrict__ h016) {
    __shared__ float xs[64 * 128];     // [row][kg^swz] at float4 granularity
    int t = threadIdx.x;
    int nodeBase = blockIdx.x * 64;

    {
        int nl = t >> 2, seg = t & 3;
        int n = nodeBase + nl;
        int swz = (nl ^ (nl >> 3)) & 7;
        float4* dstrow = (float4*)(xs + nl * 128);
        if (n < N_NODES) {
            const float4* src = (const float4*)(x + (size_t)n * IN_CH + seg * 32);
#pragma unroll
            for (int q = 0; q < 8; q++) dstrow[(seg * 8 + q) ^ swz] = src[q];
        } else {
            float4 z = {0.f, 0.f, 0.f, 0.f};
#pragma unroll
            for (int q = 0; q < 8; q++) dstrow[(seg * 8 + q) ^ swz] = z;
        }
    }
    __syncthreads();

    int tx = t & 15, ty = t >> 4;
    int n0 = tx * 4, o0 = ty * 4;     // nodes on tx, outputs on ty
    int swz0 = ((n0 + 0) ^ ((n0 + 0) >> 3)) & 7;
    int swz1 = ((n0 + 1) ^ ((n0 + 1) >> 3)) & 7;
    int swz2 = ((n0 + 2) ^ ((n0 + 2) >> 3)) & 7;
    int swz3 = ((n0 + 3) ^ ((n0 + 3) >> 3)) & 7;
    const float4* xrow0 = (const float4*)(xs + (n0 + 0) * 128);
    const float4* xrow1 = (const float4*)(xs + (n0 + 1) * 128);
    const float4* xrow2 = (const float4*)(xs + (n0 + 2) * 128);
    const float4* xrow3 = (const float4*)(xs + (n0 + 3) * 128);

    float c[4][4];
#pragma unroll
    for (int i = 0; i < 4; i++)
#pragma unroll
        for (int j = 0; j < 4; j++) c[i][j] = 0.f;

#pragma unroll 4
    for (int k = 0; k < IN_CH; k += 4) {
        int kk = k >> 2;
        float4 b0 = *(const float4*)&w[(size_t)(o0 + 0) * IN_CH + k];
        float4 b1 = *(const float4*)&w[(size_t)(o0 + 1) * IN_CH + k];
        float4 b2 = *(const float4*)&w[(size_t)(o0 + 2) * IN_CH + k];
        float4 b3 = *(const float4*)&w[(size_t)(o0 + 3) * IN_CH + k];
        float4 a0 = xrow0[kk ^ swz0];
        float4 a1 = xrow1[kk ^ swz1];
        float4 a2 = xrow2[kk ^ swz2];
        float4 a3 = xrow3[kk ^ swz3];
#pragma unroll
        for (int i = 0; i < 4; i++) {
            float4 a = (i == 0) ? a0 : (i == 1) ? a1 : (i == 2) ? a2 : a3;
            c[i][0] = fmaf(a.x, b0.x, fmaf(a.y, b0.y, fmaf(a.z, b0.z, fmaf(a.w, b0.w, c[i][0]))));
            c[i][1] = fmaf(a.x, b1.x, fmaf(a.y, b1.y, fmaf(a.z, b1.z, fmaf(a.w, b1.w, c[i][1]))));
            c[i][2] = fmaf(a.x, b2.x, fmaf(a.y, b2.y, fmaf(a.z, b2.z, fmaf(a.w, b2.w, c[i][2]))));
            c[i][3] = fmaf(a.x, b3.x, fmaf(a.y, b3.y, fmaf(a.z, b3.z, fmaf(a.w, b3.w, c[i][3]))));
        }
    }

    float4 bias = *(const float4*)&b[o0];
#pragma unroll
    for (int i = 0; i < 4; i++) {
        int n = nodeBase + n0 + i;
        if (n < N_NODES) {
            float4 v;
            v.x = fmaxf(c[i][0] + bias.x, 0.f);
            v.y = fmaxf(c[i][1] + bias.y, 0.f);
            v.z = fmaxf(c[i][2] + bias.z, 0.f);
            v.w = fmaxf(c[i][3] + bias.w, 0.f);
            *(float4*)&h0[(size_t)n * NHID + o0] = v;
            store_h4(&h016[(size_t)n * NHID + o0], v.x, v.y, v.z, v.w);
        }
    }
}

// ------- fused GCN2Conv layer -------
// New: the block's whole CSR edge range (contiguous, mean 512 edges) is staged
// into LDS coalesced, removing the e8-meta global load from the per-batch
// critical path (meta->gather serial chain was ~800cy; now gather-only).
// Value gathers are pipelined 2 batches deep (8 dwordx4 in flight per lane),
// statically indexed (pvA/pvB) to stay in registers.

__global__ __launch_bounds__(256, 4) void k_conv(const __half* __restrict__ hin,
                                                 const float* __restrict__ h0,
                                                 const int* __restrict__ rowptr,
                                                 const int2* __restrict__ e8,
                                                 const float* __restrict__ W,   // [c][o] 64x64
                                                 __half* __restrict__ hout) {
    __shared__ int2  eS[ECAP];
    __shared__ float mix[32 * 68];
    int t = threadIdx.x;
    int nodeBase = blockIdx.x * 32;      // N_NODES % 32 == 0
    int grp = t >> 3;                    // 32 groups of 8 lanes -> 1 node each
    int cg = (t & 7) * 8;                // 8 channels per lane

    int base0 = rowptr[nodeBase];
    int nE = rowptr[nodeBase + 32] - base0;
    int nStage = (nE < ECAP) ? nE : ECAP;
    for (int i = t; i < nStage; i += 256) eS[i] = e8[base0 + i];

    int n = nodeBase + grp;
    int s = rowptr[n], e = rowptr[n + 1];
    int d = e - s;
    int hi = (d > 0) ? (e - 1) : 0;
    __syncthreads();

    float acc[8];
#pragma unroll
    for (int i = 0; i < 8; i++) acc[i] = 0.f;

    // meta fetch: LDS in the (always-taken) staged case; global fallback never taken
#define LOADM(pm, jb)                                                    \
    {                                                                    \
        _Pragma("unroll")                                                \
        for (int u = 0; u < 4; u++) {                                    \
            int idx = min((jb) + u, hi);                                 \
            int li = idx - base0;                                        \
            if (li < ECAP) pm[u] = eS[li];                               \
            else           pm[u] = e8[idx];                              \
        }                                                                \
    }
#define ISSUE(pv, pm)                                                    \
    {                                                                    \
        _Pragma("unroll")                                                \
        for (int u = 0; u < 4; u++)                                      \
            pv[u] = *(const float4*)&hin[(size_t)pm[u].x * NHID + cg];   \
    }
#define FMA4(cm, cv, jb)                                                 \
    {                                                                    \
        _Pragma("unroll")                                                \
        for (int u = 0; u < 4; u++) {                                    \
            float wgt = ((jb) + u < e) ? __int_as_float(cm[u].y) : 0.f;  \
            const __half2* hp = (const __half2*)&cv[u];                  \
            _Pragma("unroll")                                            \
            for (int q = 0; q < 4; q++) {                                \
                float2 f = __half22float2(hp[q]);                        \
                acc[q * 2 + 0] = fmaf(wgt, f.x, acc[q * 2 + 0]);         \
                acc[q * 2 + 1] = fmaf(wgt, f.y, acc[q * 2 + 1]);         \
            }                                                            \
        }                                                                \
    }

    int2  pmA[4], pmB[4];
    float4 pvA[4], pvB[4];
    if (d > 0) {
        LOADM(pmA, s);     ISSUE(pvA, pmA);
        LOADM(pmB, s + 4); ISSUE(pvB, pmB);
    }

    for (int j = s; j < e; j += 8) {
        {
            int2 cm[4]; float4 cv[4];
#pragma unroll
            for (int u = 0; u < 4; u++) { cm[u] = pmA[u]; cv[u] = pvA[u]; }
            int jn = j + 8;
            if (jn < e) { LOADM(pmA, jn); ISSUE(pvA, pmA); }
            FMA4(cm, cv, j);
        }
        if (j + 4 < e) {
            int2 cm[4]; float4 cv[4];
#pragma unroll
            for (int u = 0; u < 4; u++) { cm[u] = pmB[u]; cv[u] = pvB[u]; }
            int jn = j + 12;
            if (jn < e) { LOADM(pmB, jn); ISSUE(pvB, pmB); }
            FMA4(cm, cv, j + 4);
        }
    }
#undef LOADM
#undef ISSUE
#undef FMA4

    {
        float4 h0a = *(const float4*)&h0[(size_t)n * NHID + cg];
        float4 h0b = *(const float4*)&h0[(size_t)n * NHID + cg + 4];
        float4 m0, m1;
        m0.x = fmaf(0.9f, acc[0], 0.1f * h0a.x);
        m0.y = fmaf(0.9f, acc[1], 0.1f * h0a.y);
        m0.z = fmaf(0.9f, acc[2], 0.1f * h0a.z);
        m0.w = fmaf(0.9f, acc[3], 0.1f * h0a.w);
        m1.x = fmaf(0.9f, acc[4], 0.1f * h0b.x);
        m1.y = fmaf(0.9f, acc[5], 0.1f * h0b.y);
        m1.z = fmaf(0.9f, acc[6], 0.1f * h0b.z);
        m1.w = fmaf(0.9f, acc[7], 0.1f * h0b.w);
        *(float4*)&mix[grp * 68 + cg] = m0;
        *(float4*)&mix[grp * 68 + cg + 4] = m1;
    }
    __syncthreads();

    // GEMM 32x64, 2x4 acc per thread; W rows broadcast via L1; fp16 output
    int tx = t & 15, ty = t >> 4;
    int o0 = tx * 4, r0 = ty * 2;
    float c[2][4];
#pragma unroll
    for (int i = 0; i < 2; i++)
#pragma unroll
        for (int j = 0; j < 4; j++) c[i][j] = 0.f;

#pragma unroll 4
    for (int k = 0; k < NHID; k += 4) {
        float4 b0 = *(const float4*)&W[(k + 0) * NHID + o0];
        float4 b1 = *(const float4*)&W[(k + 1) * NHID + o0];
        float4 b2 = *(const float4*)&W[(k + 2) * NHID + o0];
        float4 b3 = *(const float4*)&W[(k + 3) * NHID + o0];
#pragma unroll
        for (int i = 0; i < 2; i++) {
            float4 a = *(const float4*)&mix[(r0 + i) * 68 + k];
            c[i][0] = fmaf(a.x, b0.x, fmaf(a.y, b1.x, fmaf(a.z, b2.x, fmaf(a.w, b3.x, c[i][0]))));
            c[i][1] = fmaf(a.x, b0.y, fmaf(a.y, b1.y, fmaf(a.z, b2.y, fmaf(a.w, b3.y, c[i][1]))));
            c[i][2] = fmaf(a.x, b0.z, fmaf(a.y, b1.z, fmaf(a.z, b2.z, fmaf(a.w, b3.z, c[i][2]))));
            c[i][3] = fmaf(a.x, b0.w, fmaf(a.y, b1.w, fmaf(a.z, b2.w, fmaf(a.w, b3.w, c[i][3]))));
        }
    }
#pragma unroll
    for (int i = 0; i < 2; i++) {
        int n2 = nodeBase + r0 + i;
        store_h4(&hout[(size_t)n2 * NHID + o0],
                 fmaxf(c[i][0], 0.f), fmaxf(c[i][1], 0.f),
                 fmaxf(c[i][2], 0.f), fmaxf(c[i][3], 0.f));
    }
}

// ---------------- fc2: out = h @ fc2_w^T + b (h in fp16) ----------------

__global__ __launch_bounds__(256) void k_fc2(const __half* __restrict__ h,
                                             const float* __restrict__ w,
                                             const float* __restrict__ b,
                                             float* __restrict__ out) {
    __shared__ float wT[NHID * 44];
    __shared__ float hs[64 * 68];
    int t = threadIdx.x;
    int nodeBase = blockIdx.x * 64;

    for (int id = t; id < NHID * OUT_CH; id += 256) {
        int o = id >> 6, k = id & 63;
        wT[k * 44 + o] = w[id];
    }
    {
        int nl = t >> 2, seg = t & 3;
        int n = nodeBase + nl;
        float* dst = hs + nl * 68 + seg * 16;
        if (n < N_NODES) {
            float4 raw0 = *(const float4*)&h[(size_t)n * NHID + seg * 16];
            float4 raw1 = *(const float4*)&h[(size_t)n * NHID + seg * 16 + 8];
            const __half2* hp0 = (const __half2*)&raw0;
            const __half2* hp1 = (const __half2*)&raw1;
#pragma unroll
            for (int q = 0; q < 4; q++) {
                float2 f = __half22float2(hp0[q]);
                dst[q * 2 + 0] = f.x;
                dst[q * 2 + 1] = f.y;
            }
#pragma unroll
            for (int q = 0; q < 4; q++) {
                float2 f = __half22float2(hp1[q]);
                dst[8 + q * 2 + 0] = f.x;
                dst[8 + q * 2 + 1] = f.y;
            }
        } else {
#pragma unroll
            for (int q = 0; q < 16; q++) dst[q] = 0.f;
        }
    }
    __syncthreads();

    if (t < 160) {
        int tx = t % 10, ty = t / 10;
        int o0 = tx * 4, n0 = ty * 4;
        float c[4][4];
#pragma unroll
        for (int i = 0; i < 4; i++)
#pragma unroll
            for (int j = 0; j < 4; j++) c[i][j] = 0.f;

#pragma unroll 4
        for (int k = 0; k < NHID; k += 4) {
            float4 b0 = *(const float4*)&wT[(k + 0) * 44 + o0];
            float4 b1 = *(const float4*)&wT[(k + 1) * 44 + o0];
            float4 b2 = *(const float4*)&wT[(k + 2) * 44 + o0];
            float4 b3 = *(const float4*)&wT[(k + 3) * 44 + o0];
#pragma unroll
            for (int i = 0; i < 4; i++) {
                float4 a = *(const float4*)&hs[(n0 + i) * 68 + k];
                c[i][0] = fmaf(a.x, b0.x, fmaf(a.y, b1.x, fmaf(a.z, b2.x, fmaf(a.w, b3.x, c[i][0]))));
                c[i][1] = fmaf(a.x, b0.y, fmaf(a.y, b1.y, fmaf(a.z, b2.y, fmaf(a.w, b3.y, c[i][1]))));
                c[i][2] = fmaf(a.x, b0.z, fmaf(a.y, b1.z, fmaf(a.z, b2.z, fmaf(a.w, b3.z, c[i][2]))));
                c[i][3] = fmaf(a.x, b0.w, fmaf(a.y, b1.w, fmaf(a.z, b2.w, fmaf(a.w, b3.w, c[i][3]))));
            }
        }
        float4 bias = *(const float4*)&b[o0];
#pragma unroll
        for (int i = 0; i < 4; i++) {
            int n = nodeBase + n0 + i;
            if (n < N_NODES) {
                float4 v;
                v.x = c[i][0] + bias.x;
                v.y = c[i][1] + bias.y;
                v.z = c[i][2] + bias.z;
                v.w = c[i][3] + bias.w;
                *(float4*)&out[(size_t)n * OUT_CH + o0] = v;
            }
        }
    }
}

// ---------------- launch ----------------

extern "C" void kernel_launch(void* const* d_in, const int* in_sizes, int n_in,
                              void* d_out, int out_size, void* d_ws, size_t ws_size,
                              hipStream_t stream) {
    const float* x    = (const float*)d_in[0];
    const int*   ei   = (const int*)d_in[1];
    const float* fc1w = (const float*)d_in[3];
    const float* fc1b = (const float*)d_in[4];
    const float* cw   = (const float*)d_in[5];
    const float* fc2w = (const float*)d_in[6];
    const float* fc2b = (const float*)d_in[7];
    float* out = (float*)d_out;

    char* p = (char*)d_ws;
    auto alloc = [&](size_t bytes) { char* r = p; p += (bytes + 255) & ~(size_t)255; return r; };
    float*  h0     = (float*) alloc((size_t)N_NODES * NHID * 4);
    __half* h016   = (__half*)alloc((size_t)N_NODES * NHID * 2);
    __half* ha16   = (__half*)alloc((size_t)N_NODES * NHID * 2);
    __half* hb16   = (__half*)alloc((size_t)N_NODES * NHID * 2);
    int2*   e8     = (int2*)  alloc(((size_t)N_EDGES + 8) * 8);
    int2*   ebufA  = (int2*)  alloc((size_t)NBUCK * BCAP * 8);   // 14.05 MB fixed-cap buckets
    int*    cnt    = (int*)   alloc((size_t)N_NODES * 4);
    int*    rowptr = (int*)   alloc((size_t)(N_NODES + 1) * 4);
    int*    bCnt   = (int*)   alloc((size_t)NBUCK * 4);
    float*  dinv   = (float*) alloc((size_t)N_NODES * 4);
    int*    bsum   = (int*)   alloc(512 * 4);

    hipMemsetAsync(bCnt, 0, (size_t)NBUCK * 4, stream);
    k_scatA<<<(N_EDGES + 4095) / 4096, 256, 0, stream>>>(ei, bCnt, ebufA);
    k_deg  <<<NBUCK, 256, 0, stream>>>(ebufA, bCnt, cnt);
    k_scan1<<<NBLK, 256, 0, stream>>>(cnt, rowptr, bsum);
    k_scan2<<<1, 512, 0, stream>>>(bsum);
    k_scan3<<<NBLK, 256, 0, stream>>>(cnt, bsum, rowptr, dinv);
    k_scatB<<<NBUCK, 256, 0, stream>>>(ebufA, bCnt, dinv, rowptr, e8);

    int gb64 = (N_NODES + 63) / 64;   // 1563
    int gb32 = N_NODES / 32;          // 3125
    k_fc1 <<<gb64, 256, 0, stream>>>(x, fc1w, fc1b, h0, h016);
    k_conv<<<gb32, 256, 0, stream>>>(h016, h0, rowptr, e8, cw + 0 * NHID * NHID, ha16);
    k_conv<<<gb32, 256, 0, stream>>>(ha16, h0, rowptr, e8, cw + 1 * NHID * NHID, hb16);
    k_conv<<<gb32, 256, 0, stream>>>(hb16, h0, rowptr, e8, cw + 2 * NHID * NHID, ha16);
    k_conv<<<gb32, 256, 0, stream>>>(ha16, h0, rowptr, e8, cw + 3 * NHID * NHID, hb16);
    k_fc2 <<<gb64, 256, 0, stream>>>(hb16, fc2w, fc2b, out);
}

// Round 3
// 425.060 us; speedup vs baseline: 1.0613x; 1.0017x over previous
//
#include <hip/hip_runtime.h>
#include <hip/hip_fp16.h>

#define N_NODES 100000
#define N_EDGES 1600000
#define IN_CH   128
#define NHID    64
#define OUT_CH  40
#define NBLK    391    // ceil(N_NODES/256)
#define NBUCK   196    // ceil(N_NODES/512)
#define BCAP    8960   // fixed bucket capacity (mean 8163, +8 sigma)
#define ECAP    1024   // per-block edge stage (mean 512, sigma 22.6 -> +22 sigma)

// ---------------- rowptr scans ----------------

__global__ __launch_bounds__(256) void k_scan1(const int* __restrict__ cnt,
                                               int* __restrict__ rowptr,
                                               int* __restrict__ bsum) {
    __shared__ int s[256];
    int t = threadIdx.x;
    int n = blockIdx.x * 256 + t;
    int v = (n < N_NODES) ? cnt[n] : 0;
    s[t] = v;
    __syncthreads();
    for (int off = 1; off < 256; off <<= 1) {
        int add = (t >= off) ? s[t - off] : 0;
        __syncthreads();
        s[t] += add;
        __syncthreads();
    }
    int incl = s[t];
    if (n < N_NODES) rowptr[n] = incl - v;
    if (t == 255) bsum[blockIdx.x] = incl;
}

__global__ __launch_bounds__(512) void k_scan2(int* __restrict__ bsum) {
    __shared__ int s[512];
    int t = threadIdx.x;
    int v = (t < NBLK) ? bsum[t] : 0;
    s[t] = v;
    __syncthreads();
    for (int off = 1; off < 512; off <<= 1) {
        int add = (t >= off) ? s[t - off] : 0;
        __syncthreads();
        s[t] += add;
        __syncthreads();
    }
    if (t < NBLK) bsum[t] = s[t] - v;
}

__global__ __launch_bounds__(256) void k_scan3(const int* __restrict__ cnt,
                                               const int* __restrict__ bsum,
                                               int* __restrict__ rowptr,
                                               float* __restrict__ dinv) {
    int n = blockIdx.x * 256 + threadIdx.x;
    if (n < N_NODES) {
        int rp = rowptr[n] + bsum[n >> 8];
        rowptr[n] = rp;
        int c = cnt[n];
        dinv[n] = (c > 0) ? rsqrtf((float)c) : 0.0f;
    }
    if (blockIdx.x == 0 && threadIdx.x == 0) rowptr[N_NODES] = N_EDGES;
}

// ---- scatter pass A: fixed-capacity buckets by c>>9 (pure bucketing, no cnt) ----

__global__ __launch_bounds__(256) void k_scatA(const int* __restrict__ ei,
                                               int* __restrict__ bucketCnt,
                                               int2* __restrict__ ebufA) {
    __shared__ int hist[NBUCK];
    __shared__ int base[NBUCK];
    int t = threadIdx.x;
    int chunk = blockIdx.x * 4096;
    for (int i = t; i < NBUCK; i += 256) hist[i] = 0;
    __syncthreads();
#pragma unroll 4
    for (int i = 0; i < 16; i++) {
        int e = chunk + i * 256 + t;
        if (e < N_EDGES) atomicAdd(&hist[ei[N_EDGES + e] >> 9], 1);
    }
    __syncthreads();
    for (int b = t; b < NBUCK; b += 256) {
        int h = hist[b];
        base[b] = h ? atomicAdd(&bucketCnt[b], h) : 0;
    }
    __syncthreads();
#pragma unroll 4
    for (int i = 0; i < 16; i++) {
        int e = chunk + i * 256 + t;
        if (e < N_EDGES) {
            int r = ei[e], c = ei[N_EDGES + e];
            int pos = atomicAdd(&base[c >> 9], 1);
            ebufA[(size_t)(c >> 9) * BCAP + pos] = make_int2(r, c);
        }
    }
}

// ---- degree count from bucketed edges: contiguous read, LDS histogram ----

__global__ __launch_bounds__(256) void k_deg(const int2* __restrict__ ebufA,
                                             const int* __restrict__ bucketCnt,
                                             int* __restrict__ cnt) {
    __shared__ int hist[512];
    int b = blockIdx.x;
    int nodeB = b * 512;
    int t = threadIdx.x;
    for (int i = t; i < 512; i += 256) hist[i] = 0;
    __syncthreads();
    int nE = bucketCnt[b];
    const int2* src = ebufA + (size_t)b * BCAP;
    for (int i = t; i < nE; i += 256) atomicAdd(&hist[src[i].y - nodeB], 1);
    __syncthreads();
    for (int i = t; i < 512; i += 256) {
        int node = nodeB + i;
        if (node < N_NODES) cnt[node] = hist[i];
    }
}

// ---- scatter pass B: within bucket, per-NODE cursors -> exact CSR order ----

__global__ __launch_bounds__(256) void k_scatB(const int2* __restrict__ ebufA,
                                               const int* __restrict__ bucketCnt,
                                               const float* __restrict__ dinv,
                                               const int* __restrict__ rowptr,
                                               int2* __restrict__ e8) {
    __shared__ int lcur[512];
    int b = blockIdx.x;
    int nodeB = b * 512;
    int t = threadIdx.x;
    for (int i = t; i < 512; i += 256) {
        int node = nodeB + i;
        lcur[i] = (node < N_NODES) ? rowptr[node] : 0;
    }
    __syncthreads();
    int nE = bucketCnt[b];
    const int2* src = ebufA + (size_t)b * BCAP;
    for (int i = t; i < nE; i += 256) {
        int2 rc = src[i];
        float w = dinv[rc.x] * dinv[rc.y];
        int pos = atomicAdd(&lcur[rc.y - nodeB], 1);
        e8[pos] = make_int2(rc.x, __float_as_int(w));
    }
}

// ---- pack 4 floats -> 4 halves (8B) ----
__device__ __forceinline__ void store_h4(__half* dst, float a, float b, float c, float d) {
    union { uint2 u; __half2 h[2]; } pk;
    pk.h[0] = __floats2half2_rn(a, b);
    pk.h[1] = __floats2half2_rn(c, d);
    *(uint2*)dst = pk.u;
}

// ---------------- fc1: h016 = fp16(relu(x @ fc1_w^T + b)) ----------------
// Staging: per instruction, 8 rows x 8 lanes x 16B = contiguous 128B per row
// (8 cache lines/instr, was 64 discontiguous 16B pieces). LDS layout unchanged:
// float4 index (idx ^ swz(row)), swz(row) = (row ^ (row>>3)) & 7 -> both the
// staging writes and compute reads spread across all 8 bank-groups.

__global__ __launch_bounds__(256, 4) void k_fc1(const float* __restrict__ x,
                                                const float* __restrict__ w,
                                                const float* __restrict__ b,
                                                __half* __restrict__ h016) {
    __shared__ float xs[64 * 128];     // [row][f4idx ^ swz]
    int t = threadIdx.x;
    int nodeBase = blockIdx.x * 64;

    {
        int lane8 = t & 7, rhalf = t >> 3;     // 32 rows per pass
#pragma unroll
        for (int r2 = 0; r2 < 2; r2++) {
            int nl = r2 * 32 + rhalf;
            int n = nodeBase + nl;
            int swz = (nl ^ (nl >> 3)) & 7;
            float4* dstrow = (float4*)(xs + nl * 128);
            if (n < N_NODES) {
                const float4* src = (const float4*)(x + (size_t)n * IN_CH);
#pragma unroll
                for (int q = 0; q < 4; q++) dstrow[(q * 8 + lane8) ^ swz] = src[q * 8 + lane8];
            } else {
                float4 z = {0.f, 0.f, 0.f, 0.f};
#pragma unroll
                for (int q = 0; q < 4; q++) dstrow[(q * 8 + lane8) ^ swz] = z;
            }
        }
    }
    __syncthreads();

    int tx = t & 15, ty = t >> 4;
    int n0 = tx * 4, o0 = ty * 4;     // nodes on tx, outputs on ty
    int swz0 = ((n0 + 0) ^ ((n0 + 0) >> 3)) & 7;
    int swz1 = ((n0 + 1) ^ ((n0 + 1) >> 3)) & 7;
    int swz2 = ((n0 + 2) ^ ((n0 + 2) >> 3)) & 7;
    int swz3 = ((n0 + 3) ^ ((n0 + 3) >> 3)) & 7;
    const float4* xrow0 = (const float4*)(xs + (n0 + 0) * 128);
    const float4* xrow1 = (const float4*)(xs + (n0 + 1) * 128);
    const float4* xrow2 = (const float4*)(xs + (n0 + 2) * 128);
    const float4* xrow3 = (const float4*)(xs + (n0 + 3) * 128);

    float c[4][4];
#pragma unroll
    for (int i = 0; i < 4; i++)
#pragma unroll
        for (int j = 0; j < 4; j++) c[i][j] = 0.f;

#pragma unroll 4
    for (int k = 0; k < IN_CH; k += 4) {
        int kk = k >> 2;
        float4 b0 = *(const float4*)&w[(size_t)(o0 + 0) * IN_CH + k];
        float4 b1 = *(const float4*)&w[(size_t)(o0 + 1) * IN_CH + k];
        float4 b2 = *(const float4*)&w[(size_t)(o0 + 2) * IN_CH + k];
        float4 b3 = *(const float4*)&w[(size_t)(o0 + 3) * IN_CH + k];
        float4 a0 = xrow0[kk ^ swz0];
        float4 a1 = xrow1[kk ^ swz1];
        float4 a2 = xrow2[kk ^ swz2];
        float4 a3 = xrow3[kk ^ swz3];
#pragma unroll
        for (int i = 0; i < 4; i++) {
            float4 a = (i == 0) ? a0 : (i == 1) ? a1 : (i == 2) ? a2 : a3;
            c[i][0] = fmaf(a.x, b0.x, fmaf(a.y, b0.y, fmaf(a.z, b0.z, fmaf(a.w, b0.w, c[i][0]))));
            c[i][1] = fmaf(a.x, b1.x, fmaf(a.y, b1.y, fmaf(a.z, b1.z, fmaf(a.w, b1.w, c[i][1]))));
            c[i][2] = fmaf(a.x, b2.x, fmaf(a.y, b2.y, fmaf(a.z, b2.z, fmaf(a.w, b2.w, c[i][2]))));
            c[i][3] = fmaf(a.x, b3.x, fmaf(a.y, b3.y, fmaf(a.z, b3.z, fmaf(a.w, b3.w, c[i][3]))));
        }
    }

    float4 bias = *(const float4*)&b[o0];
#pragma unroll
    for (int i = 0; i < 4; i++) {
        int n = nodeBase + n0 + i;
        if (n < N_NODES) {
            store_h4(&h016[(size_t)n * NHID + o0],
                     fmaxf(c[i][0] + bias.x, 0.f), fmaxf(c[i][1] + bias.y, 0.f),
                     fmaxf(c[i][2] + bias.z, 0.f), fmaxf(c[i][3] + bias.w, 0.f));
        }
    }
}

// ------- fused GCN2Conv layer -------
// 3-deep copy-free gather pipeline: FMA(buf) then refill(buf), buffers statically
// named A/B/C (rule #20). Per-edge FMA written as fmaf(w, __half2float(h), acc)
// so the compiler can emit v_fma_mix_f32 (no separate cvt). Initial-residual mix
// reads h016 (fp16) instead of fp32 h0: -12.8MB FETCH per dispatch.

__global__ __launch_bounds__(256, 4) void k_conv(const __half* __restrict__ hin,
                                                 const __half* __restrict__ h0f16,
                                                 const int* __restrict__ rowptr,
                                                 const int2* __restrict__ e8,
                                                 const float* __restrict__ W,   // [c][o] 64x64
                                                 __half* __restrict__ hout) {
    __shared__ int2  eS[ECAP];
    __shared__ float mix[32 * 68];
    int t = threadIdx.x;
    int nodeBase = blockIdx.x * 32;      // N_NODES % 32 == 0
    int grp = t >> 3;                    // 32 groups of 8 lanes -> 1 node each
    int cg = (t & 7) * 8;                // 8 channels per lane

    int base0 = rowptr[nodeBase];
    int nE = rowptr[nodeBase + 32] - base0;
    int nStage = (nE < ECAP) ? nE : ECAP;
    for (int i = t; i < nStage; i += 256) eS[i] = e8[base0 + i];

    int n = nodeBase + grp;
    int s = rowptr[n], e = rowptr[n + 1];
    int d = e - s;
    int hi = (d > 0) ? (e - 1) : 0;
    __syncthreads();

    float acc[8];
#pragma unroll
    for (int i = 0; i < 8; i++) acc[i] = 0.f;

#define LOADM(pm, jb)                                                    \
    {                                                                    \
        _Pragma("unroll")                                                \
        for (int u = 0; u < 4; u++) {                                    \
            int idx = min((jb) + u, hi);                                 \
            int li = idx - base0;                                        \
            if (li < ECAP) pm[u] = eS[li];                               \
            else           pm[u] = e8[idx];                              \
        }                                                                \
    }
#define ISSUE(pv, pm)                                                    \
    {                                                                    \
        _Pragma("unroll")                                                \
        for (int u = 0; u < 4; u++)                                      \
            pv[u] = *(const float4*)&hin[(size_t)pm[u].x * NHID + cg];   \
    }
#define FMA4(pm, pv, jb)                                                 \
    {                                                                    \
        _Pragma("unroll")                                                \
        for (int u = 0; u < 4; u++) {                                    \
            float wgt = ((jb) + u < e) ? __int_as_float(pm[u].y) : 0.f;  \
            const __half* hp = (const __half*)&pv[u];                    \
            _Pragma("unroll")                                            \
            for (int q = 0; q < 8; q++)                                  \
                acc[q] = fmaf(wgt, __half2float(hp[q]), acc[q]);         \
        }                                                                \
    }

    int2  pmA[4], pmB[4], pmC[4];
    float4 pvA[4], pvB[4], pvC[4];
    if (d > 0) {
        LOADM(pmA, s);     ISSUE(pvA, pmA);
        LOADM(pmB, s + 4); ISSUE(pvB, pmB);
        LOADM(pmC, s + 8); ISSUE(pvC, pmC);
    }

    for (int j = s; j < e; j += 12) {
        {
            FMA4(pmA, pvA, j);
            int jn = j + 12;
            if (jn < e) { LOADM(pmA, jn); ISSUE(pvA, pmA); }
        }
        if (j + 4 < e) {
            FMA4(pmB, pvB, j + 4);
            int jn = j + 16;
            if (jn < e) { LOADM(pmB, jn); ISSUE(pvB, pmB); }
        }
        if (j + 8 < e) {
            FMA4(pmC, pvC, j + 8);
            int jn = j + 20;
            if (jn < e) { LOADM(pmC, jn); ISSUE(pvC, pmC); }
        }
    }
#undef LOADM
#undef ISSUE
#undef FMA4

    {
        float4 raw = *(const float4*)&h0f16[(size_t)n * NHID + cg];   // 8 halves
        const __half* h0h = (const __half*)&raw;
        float m[8];
#pragma unroll
        for (int q = 0; q < 8; q++)
            m[q] = fmaf(0.9f, acc[q], 0.1f * __half2float(h0h[q]));
        float4 m0 = {m[0], m[1], m[2], m[3]};
        float4 m1 = {m[4], m[5], m[6], m[7]};
        *(float4*)&mix[grp * 68 + cg] = m0;
        *(float4*)&mix[grp * 68 + cg + 4] = m1;
    }
    __syncthreads();

    // GEMM 32x64, 2x4 acc per thread; W rows broadcast via L1; fp16 output
    int tx = t & 15, ty = t >> 4;
    int o0 = tx * 4, r0 = ty * 2;
    float c[2][4];
#pragma unroll
    for (int i = 0; i < 2; i++)
#pragma unroll
        for (int j = 0; j < 4; j++) c[i][j] = 0.f;

#pragma unroll 4
    for (int k = 0; k < NHID; k += 4) {
        float4 b0 = *(const float4*)&W[(k + 0) * NHID + o0];
        float4 b1 = *(const float4*)&W[(k + 1) * NHID + o0];
        float4 b2 = *(const float4*)&W[(k + 2) * NHID + o0];
        float4 b3 = *(const float4*)&W[(k + 3) * NHID + o0];
#pragma unroll
        for (int i = 0; i < 2; i++) {
            float4 a = *(const float4*)&mix[(r0 + i) * 68 + k];
            c[i][0] = fmaf(a.x, b0.x, fmaf(a.y, b1.x, fmaf(a.z, b2.x, fmaf(a.w, b3.x, c[i][0]))));
            c[i][1] = fmaf(a.x, b0.y, fmaf(a.y, b1.y, fmaf(a.z, b2.y, fmaf(a.w, b3.y, c[i][1]))));
            c[i][2] = fmaf(a.x, b0.z, fmaf(a.y, b1.z, fmaf(a.z, b2.z, fmaf(a.w, b3.z, c[i][2]))));
            c[i][3] = fmaf(a.x, b0.w, fmaf(a.y, b1.w, fmaf(a.z, b2.w, fmaf(a.w, b3.w, c[i][3]))));
        }
    }
#pragma unroll
    for (int i = 0; i < 2; i++) {
        int n2 = nodeBase + r0 + i;
        store_h4(&hout[(size_t)n2 * NHID + o0],
                 fmaxf(c[i][0], 0.f), fmaxf(c[i][1], 0.f),
                 fmaxf(c[i][2], 0.f), fmaxf(c[i][3], 0.f));
    }
}

// ---------------- fc2: out = h @ fc2_w^T + b (h in fp16) ----------------

__global__ __launch_bounds__(256) void k_fc2(const __half* __restrict__ h,
                                             const float* __restrict__ w,
                                             const float* __restrict__ b,
                                             float* __restrict__ out) {
    __shared__ float wT[NHID * 44];
    __shared__ float hs[64 * 68];
    int t = threadIdx.x;
    int nodeBase = blockIdx.x * 64;

    for (int id = t; id < NHID * OUT_CH; id += 256) {
        int o = id >> 6, k = id & 63;
        wT[k * 44 + o] = w[id];
    }
    {
        int nl = t >> 2, seg = t & 3;
        int n = nodeBase + nl;
        float* dst = hs + nl * 68 + seg * 16;
        if (n < N_NODES) {
            float4 raw0 = *(const float4*)&h[(size_t)n * NHID + seg * 16];
            float4 raw1 = *(const float4*)&h[(size_t)n * NHID + seg * 16 + 8];
            const __half2* hp0 = (const __half2*)&raw0;
            const __half2* hp1 = (const __half2*)&raw1;
#pragma unroll
            for (int q = 0; q < 4; q++) {
                float2 f = __half22float2(hp0[q]);
                dst[q * 2 + 0] = f.x;
                dst[q * 2 + 1] = f.y;
            }
#pragma unroll
            for (int q = 0; q < 4; q++) {
                float2 f = __half22float2(hp1[q]);
                dst[8 + q * 2 + 0] = f.x;
                dst[8 + q * 2 + 1] = f.y;
            }
        } else {
#pragma unroll
            for (int q = 0; q < 16; q++) dst[q] = 0.f;
        }
    }
    __syncthreads();

    if (t < 160) {
        int tx = t % 10, ty = t / 10;
        int o0 = tx * 4, n0 = ty * 4;
        float c[4][4];
#pragma unroll
        for (int i = 0; i < 4; i++)
#pragma unroll
            for (int j = 0; j < 4; j++) c[i][j] = 0.f;

#pragma unroll 4
        for (int k = 0; k < NHID; k += 4) {
            float4 b0 = *(const float4*)&wT[(k + 0) * 44 + o0];
            float4 b1 = *(const float4*)&wT[(k + 1) * 44 + o0];
            float4 b2 = *(const float4*)&wT[(k + 2) * 44 + o0];
            float4 b3 = *(const float4*)&wT[(k + 3) * 44 + o0];
#pragma unroll
            for (int i = 0; i < 4; i++) {
                float4 a = *(const float4*)&hs[(n0 + i) * 68 + k];
                c[i][0] = fmaf(a.x, b0.x, fmaf(a.y, b1.x, fmaf(a.z, b2.x, fmaf(a.w, b3.x, c[i][0]))));
                c[i][1] = fmaf(a.x, b0.y, fmaf(a.y, b1.y, fmaf(a.z, b2.y, fmaf(a.w, b3.y, c[i][1]))));
                c[i][2] = fmaf(a.x, b0.z, fmaf(a.y, b1.z, fmaf(a.z, b2.z, fmaf(a.w, b3.z, c[i][2]))));
                c[i][3] = fmaf(a.x, b0.w, fmaf(a.y, b1.w, fmaf(a.z, b2.w, fmaf(a.w, b3.w, c[i][3]))));
            }
        }
        float4 bias = *(const float4*)&b[o0];
#pragma unroll
        for (int i = 0; i < 4; i++) {
            int n = nodeBase + n0 + i;
            if (n < N_NODES) {
                float4 v;
                v.x = c[i][0] + bias.x;
                v.y = c[i][1] + bias.y;
                v.z = c[i][2] + bias.z;
                v.w = c[i][3] + bias.w;
                *(float4*)&out[(size_t)n * OUT_CH + o0] = v;
            }
        }
    }
}

// ---------------- launch ----------------

extern "C" void kernel_launch(void* const* d_in, const int* in_sizes, int n_in,
                              void* d_out, int out_size, void* d_ws, size_t ws_size,
                              hipStream_t stream) {
    const float* x    = (const float*)d_in[0];
    const int*   ei   = (const int*)d_in[1];
    const float* fc1w = (const float*)d_in[3];
    const float* fc1b = (const float*)d_in[4];
    const float* cw   = (const float*)d_in[5];
    const float* fc2w = (const float*)d_in[6];
    const float* fc2b = (const float*)d_in[7];
    float* out = (float*)d_out;

    char* p = (char*)d_ws;
    auto alloc = [&](size_t bytes) { char* r = p; p += (bytes + 255) & ~(size_t)255; return r; };
    __half* h016   = (__half*)alloc((size_t)N_NODES * NHID * 2);
    __half* ha16   = (__half*)alloc((size_t)N_NODES * NHID * 2);
    __half* hb16   = (__half*)alloc((size_t)N_NODES * NHID * 2);
    int2*   e8     = (int2*)  alloc(((size_t)N_EDGES + 8) * 8);
    int2*   ebufA  = (int2*)  alloc((size_t)NBUCK * BCAP * 8);   // 14.05 MB fixed-cap buckets
    int*    cnt    = (int*)   alloc((size_t)N_NODES * 4);
    int*    rowptr = (int*)   alloc((size_t)(N_NODES + 1) * 4);
    int*    bCnt   = (int*)   alloc((size_t)NBUCK * 4);
    float*  dinv   = (float*) alloc((size_t)N_NODES * 4);
    int*    bsum   = (int*)   alloc(512 * 4);

    hipMemsetAsync(bCnt, 0, (size_t)NBUCK * 4, stream);
    k_scatA<<<(N_EDGES + 4095) / 4096, 256, 0, stream>>>(ei, bCnt, ebufA);
    k_deg  <<<NBUCK, 256, 0, stream>>>(ebufA, bCnt, cnt);
    k_scan1<<<NBLK, 256, 0, stream>>>(cnt, rowptr, bsum);
    k_scan2<<<1, 512, 0, stream>>>(bsum);
    k_scan3<<<NBLK, 256, 0, stream>>>(cnt, bsum, rowptr, dinv);
    k_scatB<<<NBUCK, 256, 0, stream>>>(ebufA, bCnt, dinv, rowptr, e8);

    int gb64 = (N_NODES + 63) / 64;   // 1563
    int gb32 = N_NODES / 32;          // 3125
    k_fc1 <<<gb64, 256, 0, stream>>>(x, fc1w, fc1b, h016);
    k_conv<<<gb32, 256, 0, stream>>>(h016, h016, rowptr, e8, cw + 0 * NHID * NHID, ha16);
    k_conv<<<gb32, 256, 0, stream>>>(ha16, h016, rowptr, e8, cw + 1 * NHID * NHID, hb16);
    k_conv<<<gb32, 256, 0, stream>>>(hb16, h016, rowptr, e8, cw + 2 * NHID * NHID, ha16);
    k_conv<<<gb32, 256, 0, stream>>>(ha16, h016, rowptr, e8, cw + 3 * NHID * NHID, hb16);
    k_fc2 <<<gb64, 256, 0, stream>>>(hb16, fc2w, fc2b, out);
}